// Round 2
// baseline (509.495 us; speedup 1.0000x reference)
//
#include <hip/hip_runtime.h>
#include <hip/hip_bf16.h>

typedef __attribute__((ext_vector_type(8))) short short8;
typedef __attribute__((ext_vector_type(4))) float f32x4;

#define NROWS 8192
#define SPLITK 8

__device__ inline short f2bf(float f) {
  union { float f; unsigned u; } v; v.f = f;
  unsigned r = v.u + 0x7FFFu + ((v.u >> 16) & 1u);
  return (short)(r >> 16);
}

// fc1_W [K][64] fp32 -> WT [64][K] bf16 (transposed)
__global__ __launch_bounds__(256) void convert_w_kernel(
    const float* __restrict__ W, short* __restrict__ WT, int K, int N) {
  int gid = blockIdx.x * 256 + threadIdx.x;
  if (gid >= K * N) return;
  int n = gid / K, k = gid - n * K;
  WT[gid] = f2bf(W[(size_t)k * N + n]);
}

// tT[n][m] = sum_j H[m][j] * W[j][n]  (n >= Nout rows written as zero)
__global__ __launch_bounds__(256) void small_t_kernel(
    const float* __restrict__ H, const float* __restrict__ W,
    short* __restrict__ tT, int Nout, int ldw) {
  __shared__ float Ws[64][64];
  int tid = threadIdx.x;
  for (int i = tid; i < 64 * 64; i += 256) {
    int j = i >> 6, n = i & 63;
    Ws[j][n] = (n < Nout) ? W[j * ldw + n] : 0.0f;
  }
  __syncthreads();
  int gid = blockIdx.x * 256 + tid;
  int m = gid >> 2;            // 4 threads per row
  int nq = (gid & 3) << 4;     // 16 columns each
  const float* hrow = H + (size_t)m * 64;
  float hr[64];
#pragma unroll
  for (int j = 0; j < 64; j += 4) {
    float4 v = *(const float4*)(hrow + j);
    hr[j] = v.x; hr[j + 1] = v.y; hr[j + 2] = v.z; hr[j + 3] = v.w;
  }
#pragma unroll
  for (int ni = 0; ni < 16; ++ni) {
    int n = nq + ni;
    float acc = 0.0f;
#pragma unroll
    for (int j = 0; j < 64; ++j) acc += hr[j] * Ws[j][n];
    tT[(size_t)n * NROWS + m] = f2bf(acc);
  }
}

// C_partial[splitk][8192][64] = A[8192][K] (fp32, cvt->bf16) @ BT^T (BT is [64][K] bf16)
__global__ __launch_bounds__(256) void gemm_mfma_kernel(
    const float* __restrict__ A, const short* __restrict__ BT,
    float* __restrict__ P, int K) {
  int w = threadIdx.x >> 6;
  int l = threadIdx.x & 63;
  int l15 = l & 15, kg = l >> 4;
  int m_base = blockIdx.x * 64 + w * 16;
  const float* Arow = A + (size_t)(m_base + l15) * K;
  const short* B0 = BT + (size_t)(0  + l15) * K;
  const short* B1 = BT + (size_t)(16 + l15) * K;
  const short* B2 = BT + (size_t)(32 + l15) * K;
  const short* B3 = BT + (size_t)(48 + l15) * K;
  int kchunk = K / SPLITK;
  int k0 = blockIdx.y * kchunk;
  f32x4 acc0 = {0,0,0,0}, acc1 = {0,0,0,0}, acc2 = {0,0,0,0}, acc3 = {0,0,0,0};
  for (int k = k0; k < k0 + kchunk; k += 32) {
    int kk = k + kg * 8;
    float4 a0 = *(const float4*)(Arow + kk);
    float4 a1 = *(const float4*)(Arow + kk + 4);
    short8 af;
    af[0] = f2bf(a0.x); af[1] = f2bf(a0.y); af[2] = f2bf(a0.z); af[3] = f2bf(a0.w);
    af[4] = f2bf(a1.x); af[5] = f2bf(a1.y); af[6] = f2bf(a1.z); af[7] = f2bf(a1.w);
    short8 b0 = *(const short8*)(B0 + kk);
    short8 b1 = *(const short8*)(B1 + kk);
    short8 b2 = *(const short8*)(B2 + kk);
    short8 b3 = *(const short8*)(B3 + kk);
    acc0 = __builtin_amdgcn_mfma_f32_16x16x32_bf16(af, b0, acc0, 0, 0, 0);
    acc1 = __builtin_amdgcn_mfma_f32_16x16x32_bf16(af, b1, acc1, 0, 0, 0);
    acc2 = __builtin_amdgcn_mfma_f32_16x16x32_bf16(af, b2, acc2, 0, 0, 0);
    acc3 = __builtin_amdgcn_mfma_f32_16x16x32_bf16(af, b3, acc3, 0, 0, 0);
  }
  float* Pb = P + (size_t)blockIdx.y * (NROWS * 64);
  int mr = m_base + kg * 4;   // D row = (lane>>4)*4 + reg  [measured layout]
#pragma unroll
  for (int r = 0; r < 4; ++r) {
    size_t base = (size_t)(mr + r) * 64 + l15;  // D col = lane&15
    Pb[base + 0]  = acc0[r];
    Pb[base + 16] = acc1[r];
    Pb[base + 32] = acc2[r];
    Pb[base + 48] = acc3[r];
  }
}

// sum split-K partials + bias (+ residual, relu) -> Hout or final Out[8192][40]
__global__ __launch_bounds__(256) void reduce_kernel(
    const float* __restrict__ P, const float* __restrict__ bias,
    const float* __restrict__ Hres, float* __restrict__ Hout,
    float* __restrict__ Out, int mode) {
  int gid = blockIdx.x * 256 + threadIdx.x;  // over 8192*64
  int n = gid & 63;
  float s = 0.0f;
#pragma unroll
  for (int sidx = 0; sidx < SPLITK; ++sidx)
    s += P[(size_t)sidx * (NROWS * 64) + gid];
  if (mode == 0) {
    Hout[gid] = s + bias[n];
  } else if (mode == 1) {
    float v = s + bias[n] + Hres[gid];
    Hout[gid] = v > 0.0f ? v : 0.0f;
  } else {
    if (n < 40) {
      int m = gid >> 6;
      float v = s + bias[n];
      Out[(size_t)m * 40 + n] = v > 0.0f ? v : 0.0f;
    }
  }
}

extern "C" void kernel_launch(void* const* d_in, const int* in_sizes, int n_in,
                              void* d_out, int out_size, void* d_ws, size_t ws_size,
                              hipStream_t stream) {
  const float* x     = (const float*)d_in[0];
  const float* adj1  = (const float*)d_in[1];
  // d_in[2] = adj2 : unused by the reference
  const float* fc1_W = (const float*)d_in[3];
  const float* fc1_b = (const float*)d_in[4];
  const float* W_h   = (const float*)d_in[5];
  const float* b_h   = (const float*)d_in[6];
  const float* W_out = (const float*)d_in[7];
  const float* b_out = (const float*)d_in[8];
  float* out = (float*)d_out;

  char* ws = (char*)d_ws;
  float* P   = (float*)ws;                                   // SPLITK*8192*64 f32 = 16 MiB
  float* h_a = (float*)(ws + (size_t)SPLITK * NROWS * 64 * 4);
  float* h_b = h_a + NROWS * 64;
  short* tT  = (short*)(h_b + NROWS * 64);                   // 64*8192 bf16 = 1 MiB
  short* WT  = tT + 64 * NROWS;                              // 64*1024 bf16

  // fc1: h = x @ fc1_W + b
  convert_w_kernel<<<(1024 * 64 + 255) / 256, 256, 0, stream>>>(fc1_W, WT, 1024, 64);
  gemm_mfma_kernel<<<dim3(NROWS / 64, SPLITK), 256, 0, stream>>>(x, WT, P, 1024);
  reduce_kernel<<<NROWS * 64 / 256, 256, 0, stream>>>(P, fc1_b, nullptr, h_a, nullptr, 0);

  float* hc = h_a; float* hn = h_b;
  for (int i = 0; i < 3; ++i) {
    small_t_kernel<<<NROWS * 4 / 256, 256, 0, stream>>>(hc, W_h + (size_t)i * 64 * 64, tT, 64, 64);
    gemm_mfma_kernel<<<dim3(NROWS / 64, SPLITK), 256, 0, stream>>>(adj1, tT, P, NROWS);
    reduce_kernel<<<NROWS * 64 / 256, 256, 0, stream>>>(P, b_h + (size_t)i * 64, hc, hn, nullptr, 1);
    float* t = hc; hc = hn; hn = t;
  }

  small_t_kernel<<<NROWS * 4 / 256, 256, 0, stream>>>(hc, W_out, tT, 40, 40);
  gemm_mfma_kernel<<<dim3(NROWS / 64, SPLITK), 256, 0, stream>>>(adj1, tT, P, NROWS);
  reduce_kernel<<<NROWS * 64 / 256, 256, 0, stream>>>(P, b_out, nullptr, nullptr, out, 2);
}

// Round 3
// 479.779 us; speedup vs baseline: 1.0619x; 1.0619x over previous
//
#include <hip/hip_runtime.h>
#include <hip/hip_bf16.h>

typedef __attribute__((ext_vector_type(8))) short short8;
typedef __attribute__((ext_vector_type(4))) float f32x4;

#define NROWS 8192

__device__ inline short f2bf(float f) {
  union { float f; unsigned u; } v; v.f = f;
  unsigned r = v.u + 0x7FFFu + ((v.u >> 16) & 1u);
  return (short)(r >> 16);
}

// fc1_W [K][64] fp32 -> WT [64][K] bf16 (transposed)
__global__ __launch_bounds__(256) void convert_w_kernel(
    const float* __restrict__ W, short* __restrict__ WT, int K, int N) {
  int gid = blockIdx.x * 256 + threadIdx.x;
  if (gid >= K * N) return;
  int n = gid / K, k = gid - n * K;
  WT[gid] = f2bf(W[(size_t)k * N + n]);
}

// tT[n][m] = sum_j H[m][j] * W[j][n]  (rows n >= Nout written as zero)
__global__ __launch_bounds__(256) void small_t_kernel(
    const float* __restrict__ H, const float* __restrict__ W,
    short* __restrict__ tT, int Nout, int ldw) {
  __shared__ float Ws[64][64];
  int tid = threadIdx.x;
  for (int i = tid; i < 64 * 64; i += 256) {
    int j = i >> 6, n = i & 63;
    Ws[j][n] = (n < Nout) ? W[j * ldw + n] : 0.0f;
  }
  __syncthreads();
  int gid = blockIdx.x * 256 + tid;
  int m = gid >> 2;            // 4 threads per row
  int nq = (gid & 3) << 4;     // 16 columns each
  const float* hrow = H + (size_t)m * 64;
  float hr[64];
#pragma unroll
  for (int j = 0; j < 64; j += 4) {
    float4 v = *(const float4*)(hrow + j);
    hr[j] = v.x; hr[j + 1] = v.y; hr[j + 2] = v.z; hr[j + 3] = v.w;
  }
#pragma unroll
  for (int ni = 0; ni < 16; ++ni) {
    int n = nq + ni;
    float acc = 0.0f;
#pragma unroll
    for (int j = 0; j < 64; ++j) acc += hr[j] * Ws[j][n];
    tT[(size_t)n * NROWS + m] = f2bf(acc);
  }
}

// P[y][8192][64] += A(fp32, cvt in-loop) @ BT^T ; optionally store bf16 A to AB.
// grid = (M/64, splitk)
__global__ __launch_bounds__(256) void gemm_a32_kernel(
    const float* __restrict__ A, const short* __restrict__ BT,
    float* __restrict__ P, short* __restrict__ AB, int K) {
  int w = threadIdx.x >> 6;
  int l = threadIdx.x & 63;
  int l15 = l & 15, kg = l >> 4;
  int m_base = blockIdx.x * 64 + w * 16;
  int row = m_base + l15;
  const float* Arow = A + (size_t)row * K;
  const short* B0 = BT + (size_t)(0  + l15) * K;
  const short* B1 = BT + (size_t)(16 + l15) * K;
  const short* B2 = BT + (size_t)(32 + l15) * K;
  const short* B3 = BT + (size_t)(48 + l15) * K;
  int kchunk = K / gridDim.y;
  int k0 = blockIdx.y * kchunk;
  f32x4 acc0 = {0,0,0,0}, acc1 = {0,0,0,0}, acc2 = {0,0,0,0}, acc3 = {0,0,0,0};
  for (int k = k0; k < k0 + kchunk; k += 32) {
    int kk = k + kg * 8;
    float4 a0 = *(const float4*)(Arow + kk);
    float4 a1 = *(const float4*)(Arow + kk + 4);
    short8 af;
    af[0] = f2bf(a0.x); af[1] = f2bf(a0.y); af[2] = f2bf(a0.z); af[3] = f2bf(a0.w);
    af[4] = f2bf(a1.x); af[5] = f2bf(a1.y); af[6] = f2bf(a1.z); af[7] = f2bf(a1.w);
    if (AB) *(short8*)(AB + (size_t)row * K + kk) = af;
    short8 b0 = *(const short8*)(B0 + kk);
    short8 b1 = *(const short8*)(B1 + kk);
    short8 b2 = *(const short8*)(B2 + kk);
    short8 b3 = *(const short8*)(B3 + kk);
    acc0 = __builtin_amdgcn_mfma_f32_16x16x32_bf16(af, b0, acc0, 0, 0, 0);
    acc1 = __builtin_amdgcn_mfma_f32_16x16x32_bf16(af, b1, acc1, 0, 0, 0);
    acc2 = __builtin_amdgcn_mfma_f32_16x16x32_bf16(af, b2, acc2, 0, 0, 0);
    acc3 = __builtin_amdgcn_mfma_f32_16x16x32_bf16(af, b3, acc3, 0, 0, 0);
  }
  float* Pb = P + (size_t)blockIdx.y * (NROWS * 64);
  int mr = m_base + kg * 4;
#pragma unroll
  for (int r = 0; r < 4; ++r) {
    size_t base = (size_t)(mr + r) * 64 + l15;
    Pb[base + 0]  = acc0[r];
    Pb[base + 16] = acc1[r];
    Pb[base + 32] = acc2[r];
    Pb[base + 48] = acc3[r];
  }
}

// P[y][8192][64] = AB(bf16) @ BT^T ; no conversion in the hot loop.
__global__ __launch_bounds__(256) void gemm_bf16_kernel(
    const short* __restrict__ AB, const short* __restrict__ BT,
    float* __restrict__ P, int K) {
  int w = threadIdx.x >> 6;
  int l = threadIdx.x & 63;
  int l15 = l & 15, kg = l >> 4;
  int m_base = blockIdx.x * 64 + w * 16;
  const short* Arow = AB + (size_t)(m_base + l15) * K;
  const short* B0 = BT + (size_t)(0  + l15) * K;
  const short* B1 = BT + (size_t)(16 + l15) * K;
  const short* B2 = BT + (size_t)(32 + l15) * K;
  const short* B3 = BT + (size_t)(48 + l15) * K;
  int kchunk = K / gridDim.y;
  int k0 = blockIdx.y * kchunk;
  f32x4 acc0 = {0,0,0,0}, acc1 = {0,0,0,0}, acc2 = {0,0,0,0}, acc3 = {0,0,0,0};
#pragma unroll 2
  for (int k = k0; k < k0 + kchunk; k += 32) {
    int kk = k + kg * 8;
    short8 af = *(const short8*)(Arow + kk);
    short8 b0 = *(const short8*)(B0 + kk);
    short8 b1 = *(const short8*)(B1 + kk);
    short8 b2 = *(const short8*)(B2 + kk);
    short8 b3 = *(const short8*)(B3 + kk);
    acc0 = __builtin_amdgcn_mfma_f32_16x16x32_bf16(af, b0, acc0, 0, 0, 0);
    acc1 = __builtin_amdgcn_mfma_f32_16x16x32_bf16(af, b1, acc1, 0, 0, 0);
    acc2 = __builtin_amdgcn_mfma_f32_16x16x32_bf16(af, b2, acc2, 0, 0, 0);
    acc3 = __builtin_amdgcn_mfma_f32_16x16x32_bf16(af, b3, acc3, 0, 0, 0);
  }
  float* Pb = P + (size_t)blockIdx.y * (NROWS * 64);
  int mr = m_base + kg * 4;
#pragma unroll
  for (int r = 0; r < 4; ++r) {
    size_t base = (size_t)(mr + r) * 64 + l15;
    Pb[base + 0]  = acc0[r];
    Pb[base + 16] = acc1[r];
    Pb[base + 32] = acc2[r];
    Pb[base + 48] = acc3[r];
  }
}

// sum split-K partials + bias (+ residual, relu) -> Hout or final Out[8192][40]
__global__ __launch_bounds__(256) void reduce_kernel(
    const float* __restrict__ P, const float* __restrict__ bias,
    const float* __restrict__ Hres, float* __restrict__ Hout,
    float* __restrict__ Out, int mode, int splitk) {
  int gid = blockIdx.x * 256 + threadIdx.x;  // over 8192*64
  int n = gid & 63;
  float s = 0.0f;
#pragma unroll 4
  for (int sidx = 0; sidx < splitk; ++sidx)
    s += P[(size_t)sidx * (NROWS * 64) + gid];
  if (mode == 0) {
    Hout[gid] = s + bias[n];
  } else if (mode == 1) {
    float v = s + bias[n] + Hres[gid];
    Hout[gid] = v > 0.0f ? v : 0.0f;
  } else {
    if (n < 40) {
      int m = gid >> 6;
      float v = s + bias[n];
      Out[(size_t)m * 40 + n] = v > 0.0f ? v : 0.0f;
    }
  }
}

extern "C" void kernel_launch(void* const* d_in, const int* in_sizes, int n_in,
                              void* d_out, int out_size, void* d_ws, size_t ws_size,
                              hipStream_t stream) {
  const float* x     = (const float*)d_in[0];
  const float* adj1  = (const float*)d_in[1];
  const float* fc1_W = (const float*)d_in[3];
  const float* fc1_b = (const float*)d_in[4];
  const float* W_h   = (const float*)d_in[5];
  const float* b_h   = (const float*)d_in[6];
  const float* W_out = (const float*)d_in[7];
  const float* b_out = (const float*)d_in[8];
  float* out = (float*)d_out;

  const int SK_ADJ = 16;   // split-K for adj GEMMs (2048 blocks, 32 waves/CU)
  const int SK_FC  = 8;

  char* ws = (char*)d_ws;
  size_t off = 0;
  float* P   = (float*)(ws + off); off += (size_t)SK_ADJ * NROWS * 64 * 4;  // 32 MiB
  float* h_a = (float*)(ws + off); off += (size_t)NROWS * 64 * 4;
  float* h_b = (float*)(ws + off); off += (size_t)NROWS * 64 * 4;
  short* tT  = (short*)(ws + off); off += (size_t)64 * NROWS * 2;
  short* WT  = (short*)(ws + off); off += (size_t)64 * 1024 * 2;
  size_t adjb_bytes = (size_t)NROWS * NROWS * 2;                            // 128 MiB
  short* AB  = (ws_size - off >= adjb_bytes) ? (short*)(ws + off) : nullptr;

  // fc1: h = x @ fc1_W + b
  convert_w_kernel<<<(1024 * 64 + 255) / 256, 256, 0, stream>>>(fc1_W, WT, 1024, 64);
  gemm_a32_kernel<<<dim3(NROWS / 64, SK_FC), 256, 0, stream>>>(x, WT, P, nullptr, 1024);
  reduce_kernel<<<NROWS * 64 / 256, 256, 0, stream>>>(P, fc1_b, nullptr, h_a, nullptr, 0, SK_FC);

  float* hc = h_a; float* hn = h_b;
  for (int i = 0; i < 3; ++i) {
    small_t_kernel<<<NROWS * 4 / 256, 256, 0, stream>>>(hc, W_h + (size_t)i * 64 * 64, tT, 64, 64);
    if (i == 0)  // first adj pass: compute + convert adj1 -> bf16 AB (if ws allows)
      gemm_a32_kernel<<<dim3(NROWS / 64, SK_ADJ), 256, 0, stream>>>(adj1, tT, P, AB, NROWS);
    else if (AB)
      gemm_bf16_kernel<<<dim3(NROWS / 64, SK_ADJ), 256, 0, stream>>>(AB, tT, P, NROWS);
    else
      gemm_a32_kernel<<<dim3(NROWS / 64, SK_ADJ), 256, 0, stream>>>(adj1, tT, P, nullptr, NROWS);
    reduce_kernel<<<NROWS * 64 / 256, 256, 0, stream>>>(P, b_h + (size_t)i * 64, hc, hn, nullptr, 1, SK_ADJ);
    float* t = hc; hc = hn; hn = t;
  }

  small_t_kernel<<<NROWS * 4 / 256, 256, 0, stream>>>(hc, W_out, tT, 40, 40);
  if (AB)
    gemm_bf16_kernel<<<dim3(NROWS / 64, SK_ADJ), 256, 0, stream>>>(AB, tT, P, NROWS);
  else
    gemm_a32_kernel<<<dim3(NROWS / 64, SK_ADJ), 256, 0, stream>>>(adj1, tT, P, nullptr, NROWS);
  reduce_kernel<<<NROWS * 64 / 256, 256, 0, stream>>>(P, b_out, nullptr, nullptr, out, 2, SK_ADJ);
}